// Round 16
// baseline (139.798 us; speedup 1.0000x reference)
//
#include <hip/hip_runtime.h>
#include <hip/hip_bf16.h>

#define IN_F 8192
#define OUT_F 8192
#define NROWS 128
#define CB 256
#define NSL 8                  // K-slices per grid.y
#define NSLT 16                // total partial slices (x2 k-halves in-block)
#define KSLICE (IN_F / NSL)    // 1024
#define NTB 128                // n-tile per block
#define QC (IN_F / 8)          // 1024 dwords per Qidxs row

using bf8    = __attribute__((ext_vector_type(8))) short;   // 8 bf16 (4 VGPRs)
using f32x16 = __attribute__((ext_vector_type(16))) float;  // 32x32 accum

typedef const __attribute__((address_space(1))) void* as1cv;
typedef __attribute__((address_space(3))) void* as3v;

__device__ inline float bf2f(unsigned int u) {
    union { unsigned int i; float f; } v; v.i = u << 16; return v.f;
}
__device__ inline unsigned short f2bf(float f) {
    __hip_bfloat16 h = __float2bfloat16(f);
    return *reinterpret_cast<unsigned short*>(&h);
}
__device__ inline void unpack8(uint4 v, float* f) {
    f[0] = bf2f(v.x & 0xffffu); f[1] = bf2f(v.x >> 16);
    f[2] = bf2f(v.y & 0xffffu); f[3] = bf2f(v.y >> 16);
    f[4] = bf2f(v.z & 0xffffu); f[5] = bf2f(v.z >> 16);
    f[6] = bf2f(v.w & 0xffffu); f[7] = bf2f(v.w >> 16);
}

#define FWHT_SCALE 0.011048543456039806f  // 1/sqrt(8192)

// ---------------- FWHT-4096 on 256 threads x 16 elems (round-11 proven) ----
#define FWHT16(v)                                                         \
    _Pragma("unroll")                                                     \
    for (int hb = 0; hb < 4; ++hb) {                                      \
        const int hh = 1 << hb;                                           \
        _Pragma("unroll")                                                 \
        for (int j = 0; j < 16; ++j)                                      \
            if (!(j & hh)) {                                              \
                float a_ = v[j], b_ = v[j | hh];                          \
                v[j] = a_ + b_; v[j | hh] = a_ - b_;                      \
            }                                                             \
    }

__device__ inline void fwht4096(float* v, float* lds, int t) {
    FWHT16(v)
#pragma unroll
    for (int e = 0; e < 16; ++e) lds[e * 260 + t] = v[e];
    __syncthreads();
    {
        const int base = (t & 15) * 260 + (t >> 4) * 16;
#pragma unroll
        for (int q = 0; q < 4; ++q) {
            float4 f = *reinterpret_cast<const float4*>(&lds[base + q * 4]);
            v[q * 4 + 0] = f.x; v[q * 4 + 1] = f.y;
            v[q * 4 + 2] = f.z; v[q * 4 + 3] = f.w;
        }
    }
    FWHT16(v)
    __syncthreads();
    {
        const int e = t & 15, ub = t >> 4;
#pragma unroll
        for (int i = 0; i < 16; ++i) lds[e * 260 + i * 16 + ub] = v[i];
    }
    __syncthreads();
    {
        const int e = t & 15, i = t >> 4;
#pragma unroll
        for (int ub = 0; ub < 16; ++ub) v[ub] = lds[e * 260 + i * 16 + ub];
    }
    FWHT16(v)
    __syncthreads();
    {
        const int e = t & 15, i = t >> 4;
#pragma unroll
        for (int ub = 0; ub < 16; ++ub) lds[ub * 260 + i * 16 + e] = v[ub];
    }
    __syncthreads();
    {
        const int base = (t >> 4) * 260 + (t & 15) * 16;
#pragma unroll
        for (int q = 0; q < 4; ++q) {
            float4 f = *reinterpret_cast<const float4*>(&lds[base + q * 4]);
            v[q * 4 + 0] = f.x; v[q * 4 + 1] = f.y;
            v[q * 4 + 2] = f.z; v[q * 4 + 3] = f.w;
        }
    }
}

// ---- Kernel A: xt = fwht(input/scaleWH*SU), tiled for 32x32x16 A-frags ----
// Layout: elem (R,K) at ((R>>5)*512 + (K>>4))*512 + ((K>>3)&1)*256
//         + (R&31)*8 + (K&7)   [ushort units]  (round-15 proven)
__global__ __launch_bounds__(256) void k_pre5(const float* __restrict__ in,
                                              const float* __restrict__ scaleWH,
                                              const float* __restrict__ SU,
                                              unsigned short* __restrict__ xt) {
    __shared__ float lds[4160];
    const int r = blockIdx.x, h = blockIdx.y, t = threadIdx.x;
    float v[16];
    const float4* xp = reinterpret_cast<const float4*>(in + (size_t)r * IN_F);
    const float4* sp = reinterpret_cast<const float4*>(scaleWH);
    const float4* up = reinterpret_cast<const float4*>(SU);
#pragma unroll
    for (int q = 0; q < 4; ++q) {
        float4 xl = xp[t * 4 + q],        sl = sp[t * 4 + q],        ul = up[t * 4 + q];
        float4 xh = xp[1024 + t * 4 + q], sh = sp[1024 + t * 4 + q], uh = up[1024 + t * 4 + q];
        float lo0 = xl.x / sl.x * ul.x, hi0 = xh.x / sh.x * uh.x;
        float lo1 = xl.y / sl.y * ul.y, hi1 = xh.y / sh.y * uh.y;
        float lo2 = xl.z / sl.z * ul.z, hi2 = xh.z / sh.z * uh.z;
        float lo3 = xl.w / sl.w * ul.w, hi3 = xh.w / sh.w * uh.w;
        v[q * 4 + 0] = h ? lo0 - hi0 : lo0 + hi0;
        v[q * 4 + 1] = h ? lo1 - hi1 : lo1 + hi1;
        v[q * 4 + 2] = h ? lo2 - hi2 : lo2 + hi2;
        v[q * 4 + 3] = h ? lo3 - hi3 : lo3 + hi3;
    }
    fwht4096(v, lds, t);
    const int k0 = h * 4096 + (t >> 4) * 256 + (t & 15) * 16;
    const size_t base = ((size_t)(r >> 5) * 512 + (k0 >> 4)) * 512 + (size_t)(r & 31) * 8;
#pragma unroll
    for (int half = 0; half < 2; ++half) {
        unsigned int w[4];
#pragma unroll
        for (int p = 0; p < 4; ++p) {
            unsigned int lo = f2bf(v[half * 8 + 2 * p]     * FWHT_SCALE);
            unsigned int hi = f2bf(v[half * 8 + 2 * p + 1] * FWHT_SCALE);
            w[p] = lo | (hi << 16);
        }
        *reinterpret_cast<uint4*>(xt + base + half * 256) = make_uint4(w[0], w[1], w[2], w[3]);
    }
}

// ---- Kernel B: 32x32x16 GEMM, 8 waves = 4 n-blocks x 2 k-halves ----
// grid (64, NSL); 512 thr. Wave tile 128m x 32n, K=512 (32 iters of K=16).
// Per iter: 1 q b32 + 1 cbl gather + 4 A b128 + 4 MFMA (low LDS-op rate of
// round 15 AT round 12's occupancy: 68KB LDS, 2 blocks/CU = 16 waves/CU).
// Both 32KB Qidxs halves staged up-front via global_load_lds; ONE barrier.
// k-halves write separate partial slices (slice = blockIdx.y*2 + kh).
__global__ __launch_bounds__(512, 4) void k_gemm13(
        const unsigned short* __restrict__ xt,
        const int* __restrict__ Qidxs,
        const float* __restrict__ cb,
        const float* __restrict__ wscale,
        unsigned short* __restrict__ pout) {
    __shared__ __align__(16) unsigned short cbl[CB][8];   // 4 KB
    __shared__ __align__(16) int Qlds[2][8192];           // 2 x 32 KB k-halves
    const int tid = threadIdx.x;
    const int wave = tid >> 6, lane = tid & 63;
    const int nblk = wave & 3, kh = wave >> 2;
    const int ln31 = lane & 31, lh = lane >> 5;
    const int n0 = blockIdx.x * NTB;
    const int ks0 = blockIdx.y * KSLICE;
    const int ksb2 = ks0 >> 4;          // global 16-k tile base
    const int c0 = ks0 >> 3;            // dword col base in Qidxs row

    // stage half h (128 rows x 64 dwords): wave-uniform LDS base + lane*16B;
    // global col-group pre-swizzled by (row & 7). (round-12 proven pattern)
    auto stageQ = [&](int h) {
#pragma unroll
        for (int j = 0; j < 4; ++j) {
            const int row = j * 32 + wave * 4 + (lane >> 4);
            const int cgs = (lane & 15) ^ (row & 7);
            const int* g = Qidxs + (size_t)(n0 + row) * QC + c0 + h * 64 + cgs * 4;
            as3v l = (as3v)(&Qlds[h][(j * 32 + wave * 4) * 64]);
            __builtin_amdgcn_global_load_lds((as1cv)(const void*)g, l, 16, 0, 0);
        }
    };

    stageQ(0);
    stageQ(1);
    const float wsc = wscale[0];
    for (int e = tid; e < CB * 8; e += 512) cbl[e >> 3][e & 7] = f2bf(cb[e] * wsc);

    f32x16 acc[4];
#pragma unroll
    for (int mt = 0; mt < 4; ++mt)
#pragma unroll
        for (int r2 = 0; r2 < 16; ++r2) acc[mt][r2] = 0.f;

    // A base pointers per m-block (frag = contiguous 1KB per 16-k tile)
    const unsigned short* xw0 = xt + ((size_t)(0 * 512) + ksb2 + kh * 32) * 512 + lane * 8;
    const unsigned short* xw1 = xt + ((size_t)(1 * 512) + ksb2 + kh * 32) * 512 + lane * 8;
    const unsigned short* xw2 = xt + ((size_t)(2 * 512) + ksb2 + kh * 32) * 512 + lane * 8;
    const unsigned short* xw3 = xt + ((size_t)(3 * 512) + ksb2 + kh * 32) * 512 + lane * 8;

    const int qrow = nblk * 32 + ln31;   // this lane's n-row within block
    const int qs7 = qrow & 7;
    const int qb = qrow * 64;

    // q col within half for iter ITL: c = ITL*2 + lh; stored col swizzled
#define QR(ITL) (Qlds[kh][qb + (((((ITL) * 2 + lh) >> 2) ^ qs7) << 2) + (((ITL) * 2 + lh) & 3)])
#define GA(Q) (*(const bf8*)&cbl[(Q)][0])
#define LA(D, IT) {                                                           \
        D##0 = *(const bf8*)(xw0 + (size_t)(IT) * 512);                       \
        D##1 = *(const bf8*)(xw1 + (size_t)(IT) * 512);                       \
        D##2 = *(const bf8*)(xw2 + (size_t)(IT) * 512);                       \
        D##3 = *(const bf8*)(xw3 + (size_t)(IT) * 512); }
#define MFMA4(A_, B_) {                                                       \
        acc[0] = __builtin_amdgcn_mfma_f32_32x32x16_bf16(A_##0, B_, acc[0], 0, 0, 0); \
        acc[1] = __builtin_amdgcn_mfma_f32_32x32x16_bf16(A_##1, B_, acc[1], 0, 0, 0); \
        acc[2] = __builtin_amdgcn_mfma_f32_32x32x16_bf16(A_##2, B_, acc[2], 0, 0, 0); \
        acc[3] = __builtin_amdgcn_mfma_f32_32x32x16_bf16(A_##3, B_, acc[3], 0, 0, 0); }

    __syncthreads();     // cbl + both Q halves staged (only barrier)

    {
        int qE = QR(0), qO = QR(1);
        bf8 aE0, aE1, aE2, aE3, aO0, aO1, aO2, aO3;
        LA(aE, 0) LA(aO, 1)
        bf8 bE = GA(qE), bO;
#pragma unroll
        for (int i2 = 0; i2 < 16; ++i2) {
            const int itl = i2 * 2;
            if (i2 < 15) qE = QR(itl + 2);
            bO = GA(qO);
            MFMA4(aE, bE)
            if (i2 < 15) LA(aE, itl + 2)
            if (i2 < 15) qO = QR(itl + 3);
            if (i2 < 15) bE = GA(qE);
            MFMA4(aO, bO)
            if (i2 < 15) LA(aO, itl + 3)
        }
    }
#undef MFMA4
#undef LA
#undef GA
#undef QR

    // epilogue: 32x32 C/D: col = lane&31, row = (reg&3)+8*(reg>>2)+4*lh
    unsigned short* ps = pout + (size_t)(blockIdx.y * 2 + kh) * (NROWS * OUT_F);
    const int col = n0 + nblk * 32 + ln31;
#pragma unroll
    for (int mt = 0; mt < 4; ++mt)
#pragma unroll
        for (int r2 = 0; r2 < 16; ++r2) {
            const int row = mt * 32 + (r2 & 3) + 8 * (r2 >> 2) + 4 * lh;
            ps[(size_t)row * OUT_F + col] = f2bf(acc[mt][r2]);
        }
}

// ---- Kernel C: out = fwht(sum of 16 slices)*SV + bias, grid (128,2) ----
__global__ __launch_bounds__(256) void k_post5(const unsigned short* __restrict__ pin,
                                               const float* __restrict__ SV,
                                               const float* __restrict__ bias,
                                               float* __restrict__ out) {
    __shared__ float lds[4160];
    const int r = blockIdx.x, h = blockIdx.y, t = threadIdx.x;
    float lo[16], hi[16], v[16];
#pragma unroll
    for (int j = 0; j < 16; ++j) { lo[j] = 0.f; hi[j] = 0.f; }
#pragma unroll 1
    for (int sl = 0; sl < NSLT; ++sl) {
        const uint4* pl = reinterpret_cast<const uint4*>(
            pin + (size_t)sl * NROWS * OUT_F + (size_t)r * OUT_F + t * 16);
        const uint4* ph = reinterpret_cast<const uint4*>(
            pin + (size_t)sl * NROWS * OUT_F + (size_t)r * OUT_F + 4096 + t * 16);
        float a[8], b[8];
        unpack8(pl[0], a); unpack8(pl[1], b);
#pragma unroll
        for (int j = 0; j < 8; ++j) { lo[j] += a[j]; lo[8 + j] += b[j]; }
        unpack8(ph[0], a); unpack8(ph[1], b);
#pragma unroll
        for (int j = 0; j < 8; ++j) { hi[j] += a[j]; hi[8 + j] += b[j]; }
    }
#pragma unroll
    for (int j = 0; j < 16; ++j) v[j] = h ? lo[j] - hi[j] : lo[j] + hi[j];
    fwht4096(v, lds, t);
    const int cb4 = (h * 4096 + (t >> 4) * 256 + (t & 15) * 16) >> 2;
    const float4* svp = reinterpret_cast<const float4*>(SV);
    const float4* bip = reinterpret_cast<const float4*>(bias);
    float4* op = reinterpret_cast<float4*>(out + (size_t)r * OUT_F);
#pragma unroll
    for (int q = 0; q < 4; ++q) {
        float4 sv = svp[cb4 + q], bi = bip[cb4 + q], o;
        o.x = v[q * 4 + 0] * FWHT_SCALE * sv.x + bi.x;
        o.y = v[q * 4 + 1] * FWHT_SCALE * sv.y + bi.y;
        o.z = v[q * 4 + 2] * FWHT_SCALE * sv.z + bi.z;
        o.w = v[q * 4 + 3] * FWHT_SCALE * sv.w + bi.w;
        op[cb4 + q] = o;
    }
}

extern "C" void kernel_launch(void* const* d_in, const int* in_sizes, int n_in,
                              void* d_out, int out_size, void* d_ws, size_t ws_size,
                              hipStream_t stream) {
    const float* in      = (const float*)d_in[0];
    const int*   Qidxs   = (const int*)d_in[1];
    const float* cb      = (const float*)d_in[2];
    const float* scaleWH = (const float*)d_in[3];
    const float* SU      = (const float*)d_in[4];
    const float* SV      = (const float*)d_in[5];
    const float* wscale  = (const float*)d_in[6];
    const float* bias    = (const float*)d_in[7];
    float* out = (float*)d_out;

    unsigned short* xt    = (unsigned short*)d_ws;                    // 2 MB (tiled)
    unsigned short* parts = (unsigned short*)((char*)d_ws
                            + (size_t)NROWS * IN_F * 2);              // 32 MB (16 slices)

    k_pre5<<<dim3(NROWS, 2), 256, 0, stream>>>(in, scaleWH, SU, xt);
    k_gemm13<<<dim3(OUT_F / NTB, NSL), 512, 0, stream>>>(xt, Qidxs, cb, wscale, parts);
    k_post5<<<dim3(NROWS, 2), 256, 0, stream>>>(parts, SV, bias, out);
}

// Round 17
// 50.604 us; speedup vs baseline: 2.7626x; 2.7626x over previous
//
#include <hip/hip_runtime.h>
#include <hip/hip_bf16.h>

#define IN_F 8192
#define OUT_F 8192
#define NROWS 128
#define CB 256
#define NSL 8                  // K-slices per grid.y
#define NSLT 16                // total partial slices (x2 k-halves in-block)
#define KSLICE (IN_F / NSL)    // 1024
#define NTB 128                // n-tile per block
#define QC (IN_F / 8)          // 1024 dwords per Qidxs row

using bf8    = __attribute__((ext_vector_type(8))) short;   // 8 bf16 (4 VGPRs)
using f32x16 = __attribute__((ext_vector_type(16))) float;  // 32x32 accum

typedef const __attribute__((address_space(1))) void* as1cv;
typedef __attribute__((address_space(3))) void* as3v;

__device__ inline float bf2f(unsigned int u) {
    union { unsigned int i; float f; } v; v.i = u << 16; return v.f;
}
__device__ inline unsigned short f2bf(float f) {
    __hip_bfloat16 h = __float2bfloat16(f);
    return *reinterpret_cast<unsigned short*>(&h);
}
__device__ inline void unpack8(uint4 v, float* f) {
    f[0] = bf2f(v.x & 0xffffu); f[1] = bf2f(v.x >> 16);
    f[2] = bf2f(v.y & 0xffffu); f[3] = bf2f(v.y >> 16);
    f[4] = bf2f(v.z & 0xffffu); f[5] = bf2f(v.z >> 16);
    f[6] = bf2f(v.w & 0xffffu); f[7] = bf2f(v.w >> 16);
}

#define FWHT_SCALE 0.011048543456039806f  // 1/sqrt(8192)

// ---------------- FWHT-4096 on 256 threads x 16 elems (round-11 proven) ----
#define FWHT16(v)                                                         \
    _Pragma("unroll")                                                     \
    for (int hb = 0; hb < 4; ++hb) {                                      \
        const int hh = 1 << hb;                                           \
        _Pragma("unroll")                                                 \
        for (int j = 0; j < 16; ++j)                                      \
            if (!(j & hh)) {                                              \
                float a_ = v[j], b_ = v[j | hh];                          \
                v[j] = a_ + b_; v[j | hh] = a_ - b_;                      \
            }                                                             \
    }

__device__ inline void fwht4096(float* v, float* lds, int t) {
    FWHT16(v)
#pragma unroll
    for (int e = 0; e < 16; ++e) lds[e * 260 + t] = v[e];
    __syncthreads();
    {
        const int base = (t & 15) * 260 + (t >> 4) * 16;
#pragma unroll
        for (int q = 0; q < 4; ++q) {
            float4 f = *reinterpret_cast<const float4*>(&lds[base + q * 4]);
            v[q * 4 + 0] = f.x; v[q * 4 + 1] = f.y;
            v[q * 4 + 2] = f.z; v[q * 4 + 3] = f.w;
        }
    }
    FWHT16(v)
    __syncthreads();
    {
        const int e = t & 15, ub = t >> 4;
#pragma unroll
        for (int i = 0; i < 16; ++i) lds[e * 260 + i * 16 + ub] = v[i];
    }
    __syncthreads();
    {
        const int e = t & 15, i = t >> 4;
#pragma unroll
        for (int ub = 0; ub < 16; ++ub) v[ub] = lds[e * 260 + i * 16 + ub];
    }
    FWHT16(v)
    __syncthreads();
    {
        const int e = t & 15, i = t >> 4;
#pragma unroll
        for (int ub = 0; ub < 16; ++ub) lds[ub * 260 + i * 16 + e] = v[ub];
    }
    __syncthreads();
    {
        const int base = (t >> 4) * 260 + (t & 15) * 16;
#pragma unroll
        for (int q = 0; q < 4; ++q) {
            float4 f = *reinterpret_cast<const float4*>(&lds[base + q * 4]);
            v[q * 4 + 0] = f.x; v[q * 4 + 1] = f.y;
            v[q * 4 + 2] = f.z; v[q * 4 + 3] = f.w;
        }
    }
}

// ---- Kernel A: xt = fwht(input/scaleWH*SU), tiled for 32x32x16 A-frags ----
// Layout: elem (R,K) at ((R>>5)*512 + (K>>4))*512 + ((K>>3)&1)*256
//         + (R&31)*8 + (K&7)   [ushort units]  (round-15 proven)
__global__ __launch_bounds__(256) void k_pre5(const float* __restrict__ in,
                                              const float* __restrict__ scaleWH,
                                              const float* __restrict__ SU,
                                              unsigned short* __restrict__ xt) {
    __shared__ float lds[4160];
    const int r = blockIdx.x, h = blockIdx.y, t = threadIdx.x;
    float v[16];
    const float4* xp = reinterpret_cast<const float4*>(in + (size_t)r * IN_F);
    const float4* sp = reinterpret_cast<const float4*>(scaleWH);
    const float4* up = reinterpret_cast<const float4*>(SU);
#pragma unroll
    for (int q = 0; q < 4; ++q) {
        float4 xl = xp[t * 4 + q],        sl = sp[t * 4 + q],        ul = up[t * 4 + q];
        float4 xh = xp[1024 + t * 4 + q], sh = sp[1024 + t * 4 + q], uh = up[1024 + t * 4 + q];
        float lo0 = xl.x / sl.x * ul.x, hi0 = xh.x / sh.x * uh.x;
        float lo1 = xl.y / sl.y * ul.y, hi1 = xh.y / sh.y * uh.y;
        float lo2 = xl.z / sl.z * ul.z, hi2 = xh.z / sh.z * uh.z;
        float lo3 = xl.w / sl.w * ul.w, hi3 = xh.w / sh.w * uh.w;
        v[q * 4 + 0] = h ? lo0 - hi0 : lo0 + hi0;
        v[q * 4 + 1] = h ? lo1 - hi1 : lo1 + hi1;
        v[q * 4 + 2] = h ? lo2 - hi2 : lo2 + hi2;
        v[q * 4 + 3] = h ? lo3 - hi3 : lo3 + hi3;
    }
    fwht4096(v, lds, t);
    const int k0 = h * 4096 + (t >> 4) * 256 + (t & 15) * 16;
    const size_t base = ((size_t)(r >> 5) * 512 + (k0 >> 4)) * 512 + (size_t)(r & 31) * 8;
#pragma unroll
    for (int half = 0; half < 2; ++half) {
        unsigned int w[4];
#pragma unroll
        for (int p = 0; p < 4; ++p) {
            unsigned int lo = f2bf(v[half * 8 + 2 * p]     * FWHT_SCALE);
            unsigned int hi = f2bf(v[half * 8 + 2 * p + 1] * FWHT_SCALE);
            w[p] = lo | (hi << 16);
        }
        *reinterpret_cast<uint4*>(xt + base + half * 256) = make_uint4(w[0], w[1], w[2], w[3]);
    }
}

// ---- Kernel B: 32x32x16 GEMM, 8 waves = 2 mgrp x 2 ngrp x 2 kh ----
// grid (64, NSL); 512 thr. Wave tile 64m x 64n (acc[2][2] = 64 VGPR),
// K=512 per kh (32 iters of K=16). Per iter: 2 A b128 (L1-shared), 2 q b32,
// 2 cbl gathers, 4 MFMA. A-delivery 1MB/CU, gather ratio 1:2, 16 waves/CU.
// Both 32KB Qidxs halves staged up-front (global_load_lds); ONE barrier.
// k-halves write separate partial slices (slice = blockIdx.y*2 + kh).
__global__ __launch_bounds__(512, 4) void k_gemm14(
        const unsigned short* __restrict__ xt,
        const int* __restrict__ Qidxs,
        const float* __restrict__ cb,
        const float* __restrict__ wscale,
        unsigned short* __restrict__ pout) {
    __shared__ __align__(16) unsigned short cbl[CB][8];   // 4 KB
    __shared__ __align__(16) int Qlds[2][8192];           // 2 x 32 KB k-halves
    const int tid = threadIdx.x;
    const int wave = tid >> 6, lane = tid & 63;
    const int ngrp = wave & 1, mgrp = (wave >> 1) & 1, kh = wave >> 2;
    const int ln31 = lane & 31, lh = lane >> 5;
    const int n0 = blockIdx.x * NTB;
    const int ks0 = blockIdx.y * KSLICE;
    const int ksb2 = ks0 >> 4;          // global 16-k tile base
    const int c0 = ks0 >> 3;            // dword col base in Qidxs row

    // stage half h (128 rows x 64 dwords): wave-uniform LDS base + lane*16B;
    // global col-group pre-swizzled by (row & 7). (round-12/16 proven)
    auto stageQ = [&](int h) {
#pragma unroll
        for (int j = 0; j < 4; ++j) {
            const int row = j * 32 + wave * 4 + (lane >> 4);
            const int cgs = (lane & 15) ^ (row & 7);
            const int* g = Qidxs + (size_t)(n0 + row) * QC + c0 + h * 64 + cgs * 4;
            as3v l = (as3v)(&Qlds[h][(j * 32 + wave * 4) * 64]);
            __builtin_amdgcn_global_load_lds((as1cv)(const void*)g, l, 16, 0, 0);
        }
    };

    stageQ(0);
    stageQ(1);
    const float wsc = wscale[0];
    for (int e = tid; e < CB * 8; e += 512) cbl[e >> 3][e & 7] = f2bf(cb[e] * wsc);

    f32x16 acc00, acc01, acc10, acc11;
#pragma unroll
    for (int r2 = 0; r2 < 16; ++r2) { acc00[r2] = 0.f; acc01[r2] = 0.f;
                                      acc10[r2] = 0.f; acc11[r2] = 0.f; }

    // A base pointers for this wave's 2 m-blocks (frag = contiguous 1KB)
    const unsigned short* xwA = xt + ((size_t)((mgrp * 2 + 0) * 512) + ksb2 + kh * 32) * 512 + lane * 8;
    const unsigned short* xwB = xt + ((size_t)((mgrp * 2 + 1) * 512) + ksb2 + kh * 32) * 512 + lane * 8;

    // Qidxs rows for this wave's 2 n-blocks
    const int qrow0 = ngrp * 64 + ln31;
    const int qrow1 = ngrp * 64 + 32 + ln31;
    const int qb0 = qrow0 * 64, qs0 = qrow0 & 7;
    const int qb1 = qrow1 * 64, qs1 = qrow1 & 7;

#define QR0(ITL) (Qlds[kh][qb0 + (((((ITL) * 2 + lh) >> 2) ^ qs0) << 2) + (((ITL) * 2 + lh) & 3)])
#define QR1(ITL) (Qlds[kh][qb1 + (((((ITL) * 2 + lh) >> 2) ^ qs1) << 2) + (((ITL) * 2 + lh) & 3)])
#define GA(Q) (*(const bf8*)&cbl[(Q)][0])
#define MFMA4(A0_, A1_, B0_, B1_) {                                           \
        acc00 = __builtin_amdgcn_mfma_f32_32x32x16_bf16(A0_, B0_, acc00, 0, 0, 0); \
        acc01 = __builtin_amdgcn_mfma_f32_32x32x16_bf16(A0_, B1_, acc01, 0, 0, 0); \
        acc10 = __builtin_amdgcn_mfma_f32_32x32x16_bf16(A1_, B0_, acc10, 0, 0, 0); \
        acc11 = __builtin_amdgcn_mfma_f32_32x32x16_bf16(A1_, B1_, acc11, 0, 0, 0); }

    __syncthreads();     // cbl + both Q halves staged (only barrier)

    {
        int q0 = QR0(0), q1 = QR1(0);
        bf8 bA0 = GA(q0), bA1 = GA(q1);
        bf8 bB0, bB1;
#pragma unroll
        for (int i2 = 0; i2 < 16; ++i2) {
            const int e = i2 * 2, o = i2 * 2 + 1;
            const int en = (e + 2 > 31) ? 31 : e + 2;   // compile-time clamp
            // even iter: prefetch odd's b, load A, 4 MFMA
            q0 = QR0(o); q1 = QR1(o);
            bB0 = GA(q0); bB1 = GA(q1);
            {
                bf8 a0 = *(const bf8*)(xwA + (size_t)e * 512);
                bf8 a1 = *(const bf8*)(xwB + (size_t)e * 512);
                MFMA4(a0, a1, bA0, bA1)
            }
            // odd iter: prefetch next even's b, load A, 4 MFMA
            q0 = QR0(en); q1 = QR1(en);
            bA0 = GA(q0); bA1 = GA(q1);
            {
                bf8 a0 = *(const bf8*)(xwA + (size_t)o * 512);
                bf8 a1 = *(const bf8*)(xwB + (size_t)o * 512);
                MFMA4(a0, a1, bB0, bB1)
            }
        }
    }
#undef MFMA4
#undef GA
#undef QR1
#undef QR0

    // epilogue: 32x32 C/D: col = lane&31, row = (reg&3)+8*(reg>>2)+4*lh
    unsigned short* ps = pout + (size_t)(blockIdx.y * 2 + kh) * (NROWS * OUT_F);
    const int col0 = n0 + ngrp * 64 + ln31;
#pragma unroll
    for (int r2 = 0; r2 < 16; ++r2) {
        const int rp = (r2 & 3) + 8 * (r2 >> 2) + 4 * lh;
        const int row0 = mgrp * 64 + rp;
        const int row1 = mgrp * 64 + 32 + rp;
        ps[(size_t)row0 * OUT_F + col0]      = f2bf(acc00[r2]);
        ps[(size_t)row0 * OUT_F + col0 + 32] = f2bf(acc01[r2]);
        ps[(size_t)row1 * OUT_F + col0]      = f2bf(acc10[r2]);
        ps[(size_t)row1 * OUT_F + col0 + 32] = f2bf(acc11[r2]);
    }
}

// ---- Kernel C: out = fwht(sum of 16 slices)*SV + bias, grid (128,2) ----
__global__ __launch_bounds__(256) void k_post5(const unsigned short* __restrict__ pin,
                                               const float* __restrict__ SV,
                                               const float* __restrict__ bias,
                                               float* __restrict__ out) {
    __shared__ float lds[4160];
    const int r = blockIdx.x, h = blockIdx.y, t = threadIdx.x;
    float lo[16], hi[16], v[16];
#pragma unroll
    for (int j = 0; j < 16; ++j) { lo[j] = 0.f; hi[j] = 0.f; }
#pragma unroll 1
    for (int sl = 0; sl < NSLT; ++sl) {
        const uint4* pl = reinterpret_cast<const uint4*>(
            pin + (size_t)sl * NROWS * OUT_F + (size_t)r * OUT_F + t * 16);
        const uint4* ph = reinterpret_cast<const uint4*>(
            pin + (size_t)sl * NROWS * OUT_F + (size_t)r * OUT_F + 4096 + t * 16);
        float a[8], b[8];
        unpack8(pl[0], a); unpack8(pl[1], b);
#pragma unroll
        for (int j = 0; j < 8; ++j) { lo[j] += a[j]; lo[8 + j] += b[j]; }
        unpack8(ph[0], a); unpack8(ph[1], b);
#pragma unroll
        for (int j = 0; j < 8; ++j) { hi[j] += a[j]; hi[8 + j] += b[j]; }
    }
#pragma unroll
    for (int j = 0; j < 16; ++j) v[j] = h ? lo[j] - hi[j] : lo[j] + hi[j];
    fwht4096(v, lds, t);
    const int cb4 = (h * 4096 + (t >> 4) * 256 + (t & 15) * 16) >> 2;
    const float4* svp = reinterpret_cast<const float4*>(SV);
    const float4* bip = reinterpret_cast<const float4*>(bias);
    float4* op = reinterpret_cast<float4*>(out + (size_t)r * OUT_F);
#pragma unroll
    for (int q = 0; q < 4; ++q) {
        float4 sv = svp[cb4 + q], bi = bip[cb4 + q], o;
        o.x = v[q * 4 + 0] * FWHT_SCALE * sv.x + bi.x;
        o.y = v[q * 4 + 1] * FWHT_SCALE * sv.y + bi.y;
        o.z = v[q * 4 + 2] * FWHT_SCALE * sv.z + bi.z;
        o.w = v[q * 4 + 3] * FWHT_SCALE * sv.w + bi.w;
        op[cb4 + q] = o;
    }
}

extern "C" void kernel_launch(void* const* d_in, const int* in_sizes, int n_in,
                              void* d_out, int out_size, void* d_ws, size_t ws_size,
                              hipStream_t stream) {
    const float* in      = (const float*)d_in[0];
    const int*   Qidxs   = (const int*)d_in[1];
    const float* cb      = (const float*)d_in[2];
    const float* scaleWH = (const float*)d_in[3];
    const float* SU      = (const float*)d_in[4];
    const float* SV      = (const float*)d_in[5];
    const float* wscale  = (const float*)d_in[6];
    const float* bias    = (const float*)d_in[7];
    float* out = (float*)d_out;

    unsigned short* xt    = (unsigned short*)d_ws;                    // 2 MB (tiled)
    unsigned short* parts = (unsigned short*)((char*)d_ws
                            + (size_t)NROWS * IN_F * 2);              // 32 MB (16 slices)

    k_pre5<<<dim3(NROWS, 2), 256, 0, stream>>>(in, scaleWH, SU, xt);
    k_gemm14<<<dim3(OUT_F / NTB, NSL), 512, 0, stream>>>(xt, Qidxs, cb, wscale, parts);
    k_post5<<<dim3(NROWS, 2), 256, 0, stream>>>(parts, SV, bias, out);
}